// Round 15
// baseline (335.522 us; speedup 1.0000x reference)
//
#include <hip/hip_runtime.h>
#include <stdint.h>
#include <math.h>

typedef unsigned short u16;
typedef __bf16 bf16x8 __attribute__((ext_vector_type(8)));
typedef float f32x4 __attribute__((ext_vector_type(4)));
typedef float f32x2 __attribute__((ext_vector_type(2)));
typedef float f32x16 __attribute__((ext_vector_type(16)));
typedef unsigned short u16x8 __attribute__((ext_vector_type(8)));
typedef unsigned short u16x4 __attribute__((ext_vector_type(4)));

#define BATCH 4
#define SEQT 2048
#define DMODEL 1024
#define NHEAD 16
#define HDIM 64
#define LOG2E 1.44269504f

#define LDS_GLD16(gp, lp)                                                     \
  __builtin_amdgcn_global_load_lds(                                           \
      (const __attribute__((address_space(1))) void*)(gp),                    \
      (__attribute__((address_space(3))) void*)(lp), 16, 0, 0)

static __device__ __forceinline__ u16 f2bf(float f) {  // RNE
  union { float f; uint32_t u; } c; c.f = f;
  uint32_t u = c.u;
  return (u16)((u + 0x7fffu + ((u >> 16) & 1u)) >> 16);
}
static __device__ __forceinline__ u16 f2bf_fast(float f) {  // round-half-up
  union { float f; uint32_t u; } c; c.f = f;
  return (u16)((c.u + 0x8000u) >> 16);
}
// pack bf16(a) low 16, bf16(b) high 16 (round-half-up)
static __device__ __forceinline__ uint32_t pkbf(float a, float b) {
  union { float f; uint32_t u; } ca, cb; ca.f = a; cb.f = b;
  return __builtin_amdgcn_perm(cb.u + 0x8000u, ca.u + 0x8000u, 0x07060302u);
}
static __device__ __forceinline__ bf16x8 mk_bf8(uint32_t x0, uint32_t x1,
                                                uint32_t x2, uint32_t x3) {
  union { uint32_t u[4]; bf16x8 v; } t;
  t.u[0] = x0; t.u[1] = x1; t.u[2] = x2; t.u[3] = x3;
  return t.v;
}

// ------------------------------------------------------------ convert all ---
__global__ __launch_bounds__(256) void k_convert_all(
    const float* __restrict__ x, const float* __restrict__ Wq,
    const float* __restrict__ Wk, const float* __restrict__ Wv,
    const float* __restrict__ Wo, u16* __restrict__ xbf,
    u16* __restrict__ Wqkv, u16* __restrict__ Wob) {
  const int NX4 = 2097152, NW4 = 262144;
  int i = blockIdx.x * 256 + threadIdx.x;
  const float* s; u16* d; int js, jd;
  if (i < NX4) {
    s = x; d = xbf; js = jd = i;
  } else if (i < NX4 + 3 * NW4) {
    int j = i - NX4;
    int w = j >> 18;
    s = (w == 0) ? Wq : (w == 1) ? Wk : Wv;
    js = j & (NW4 - 1);
    d = Wqkv; jd = j;
  } else {
    s = Wo; d = Wob; js = jd = i - NX4 - 3 * NW4;
  }
  float4 v = ((const float4*)s)[js];
  u16x4 o = {f2bf(v.x), f2bf(v.y), f2bf(v.z), f2bf(v.w)};
  ((u16x4*)d)[jd] = o;
}

// ---------------------------------------------------- QK + VT merged GEMM ---
// blocks [0,1024): C = x * [Wq;Wk]^T (M=8192,N=2048), scatter Q/K [bh][t][hd]
// blocks [1024,1536): V^T = Wv * x^T (M=1024,N=8192), scatter Vt [bh][d][t']
//   with t' key-permuted within 16-groups so attention PV A-frags are
//   single contiguous b128 reads: pos(k)=(k&~15)|((k&4)<<1)|((k&8)>>1)|(k&3).
// R11: XCD-aware L2-locality remap (T1) — verified: total 297.6->295.3.
// R15: 32x32x16 MFMA (was 16x16x32). Same FLOPs in HALF the MFMA issues
//   (16 vs 32 per K-step) at ~15% better matrix-pipe rate (m119: 2495 vs
//   2176 TF). LDS traffic identical (16 b128 reads/K-step). Layouts are the
//   attn-kernel-verified ones: A row=l32 k=hi*8+e; C/D col=l32,
//   row=(r&3)+8*(r>>2)+4*hi.
__global__ __launch_bounds__(256) void k_gemm_qkvt(
    const u16* __restrict__ xbf, const u16* __restrict__ Wqk,
    const u16* __restrict__ Wv, const float* __restrict__ bq_,
    const float* __restrict__ bk_, const float* __restrict__ bv_,
    u16* __restrict__ dq, u16* __restrict__ dk, u16* __restrict__ Vt) {
  __shared__ u16 As[128 * 64];
  __shared__ u16 Bs[128 * 64];

  const int bid = blockIdx.x;
  const bool isQK = bid < 1024;
  const u16 *Ap, *Bp;
  int m0, n0;
  if (isQK) {
    const int c = bid & 7;        // XCD (dispatch round-robin)
    const int j = bid >> 3;       // 0..127
    m0 = (c * 8 + (j & 7)) * 128; // 64 m-panels; 8 per XCD, L2-resident
    n0 = (j >> 3) * 128;          // 0..15, varies slowest
    Ap = xbf; Bp = Wqk;
  } else {
    const int i2 = bid - 1024;    // 0..511 (XCD of bid = i2%8 since 1024%8=0)
    const int c = i2 & 7;
    const int j = i2 >> 3;        // 0..63
    m0 = (j >> 3) * 128;          // 0..7 (Wv panels, hot 8-consecutive)
    n0 = (c * 8 + (j & 7)) * 128; // 64 n-panels; 8 per XCD, L2-resident
    Ap = Wv; Bp = xbf;
  }

  const int tid = threadIdx.x;
  const int wave = tid >> 6, lane = tid & 63;
  const int l32 = lane & 31, hi = lane >> 5;
  const int wm = wave & 1, wn = wave >> 1;
  const int lrow = lane >> 3, lcol = (lane & 7) * 8;

  f32x16 acc[2][2] = {};

  for (int kt = 0; kt < 1024; kt += 64) {
    __syncthreads();
    for (int c = 0; c < 4; ++c) {
      int rr = (wave * 4 + c) * 8 + lrow;
      LDS_GLD16(Ap + (size_t)(m0 + rr) * 1024 + kt + lcol,
                &As[(wave * 4 + c) * 512]);
      LDS_GLD16(Bp + (size_t)(n0 + rr) * 1024 + kt + lcol,
                &Bs[(wave * 4 + c) * 512]);
    }
    __syncthreads();
    for (int kc = 0; kc < 4; ++kc) {  // K=16 chunks of the 64-wide tile
      bf16x8 af[2], bfr[2];
      for (int mt = 0; mt < 2; ++mt)
        af[mt] = *(const bf16x8*)&As[(wm * 64 + mt * 32 + l32) * 64 + kc * 16 +
                                     hi * 8];
      for (int nt = 0; nt < 2; ++nt)
        bfr[nt] = *(const bf16x8*)&Bs[(wn * 64 + nt * 32 + l32) * 64 + kc * 16 +
                                      hi * 8];
      for (int mt = 0; mt < 2; ++mt)
        for (int nt = 0; nt < 2; ++nt)
          acc[mt][nt] = __builtin_amdgcn_mfma_f32_32x32x16_bf16(
              af[mt], bfr[nt], acc[mt][nt], 0, 0, 0);
    }
  }

  if (isQK) {
    u16* dst = (n0 < 1024) ? dq : dk;
    const float* bias = (n0 < 1024) ? bq_ : bk_;
    for (int mt = 0; mt < 2; ++mt)
      for (int nt = 0; nt < 2; ++nt) {
        int nn = (n0 + wn * 64 + nt * 32 + l32) & 1023;
        float bv = bias[nn];
        int h = nn >> 6, hd = nn & 63;
        for (int r = 0; r < 16; ++r) {
          int m = m0 + wm * 64 + mt * 32 + (r & 3) + 8 * (r >> 2) + 4 * hi;
          int b = m >> 11, t = m & 2047;
          dst[(((size_t)b * NHEAD + h) * SEQT + t) * HDIM + hd] =
              f2bf_fast(acc[mt][nt][r] + bv);
        }
      }
  } else {
    for (int mt = 0; mt < 2; ++mt)
      for (int nt = 0; nt < 2; ++nt) {
        int n = n0 + wn * 64 + nt * 32 + l32;
        int b = n >> 11, t = n & 2047;
        int tp = (t & ~15) | ((t & 4) << 1) | ((t & 8) >> 1) | (t & 3);
        for (int r = 0; r < 16; ++r) {
          int m = m0 + wm * 64 + mt * 32 + (r & 3) + 8 * (r >> 2) + 4 * hi;
          float v = acc[mt][nt][r] + bv_[m];
          Vt[((size_t)(b * NHEAD + (m >> 6)) * HDIM + (m & 63)) * SEQT + tp] =
              f2bf_fast(v);
        }
      }
  }
}

// ------------------------------------------------------------ out-proj ------
// R11: 1-D grid 512, XCD remap (XCD owns 8 Obf m-panels). R15: 32x32x16.
__global__ __launch_bounds__(256) void k_gemm_proj(const u16* __restrict__ A,
                                                   const u16* __restrict__ Bm,
                                                   const float* __restrict__ bias,
                                                   float* __restrict__ out) {
  __shared__ u16 As[128 * 64];
  __shared__ u16 Bs[128 * 64];

  const int tid = threadIdx.x;
  const int wave = tid >> 6, lane = tid & 63;
  const int l32 = lane & 31, hi = lane >> 5;
  const int wm = wave & 1, wn = wave >> 1;
  const int bid = blockIdx.x;            // 0..511
  const int xc = bid & 7, j = bid >> 3;  // j 0..63
  const int m0 = (xc * 8 + (j & 7)) * 128;  // 64 m-panels; 8 per XCD
  const int n0 = (j >> 3) * 128;            // 0..7
  const int lrow = lane >> 3, lcol = (lane & 7) * 8;

  f32x16 acc[2][2] = {};

  for (int kt = 0; kt < 1024; kt += 64) {
    __syncthreads();
    for (int c = 0; c < 4; ++c) {
      int rr = (wave * 4 + c) * 8 + lrow;
      LDS_GLD16(A + (size_t)(m0 + rr) * 1024 + kt + lcol,
                &As[(wave * 4 + c) * 512]);
      LDS_GLD16(Bm + (size_t)(n0 + rr) * 1024 + kt + lcol,
                &Bs[(wave * 4 + c) * 512]);
    }
    __syncthreads();
    for (int kc = 0; kc < 4; ++kc) {
      bf16x8 af[2], bfr[2];
      for (int mt = 0; mt < 2; ++mt)
        af[mt] = *(const bf16x8*)&As[(wm * 64 + mt * 32 + l32) * 64 + kc * 16 +
                                     hi * 8];
      for (int nt = 0; nt < 2; ++nt)
        bfr[nt] = *(const bf16x8*)&Bs[(wn * 64 + nt * 32 + l32) * 64 + kc * 16 +
                                      hi * 8];
      for (int mt = 0; mt < 2; ++mt)
        for (int nt = 0; nt < 2; ++nt)
          acc[mt][nt] = __builtin_amdgcn_mfma_f32_32x32x16_bf16(
              af[mt], bfr[nt], acc[mt][nt], 0, 0, 0);
    }
  }

  for (int mt = 0; mt < 2; ++mt)
    for (int nt = 0; nt < 2; ++nt) {
      int n = n0 + wn * 64 + nt * 32 + l32;
      float bv = bias[n];
      for (int r = 0; r < 16; ++r) {
        int m = m0 + wm * 64 + mt * 32 + (r & 3) + 8 * (r >> 2) + 4 * hi;
        out[(size_t)m * 1024 + n] = acc[mt][nt][r] + bv;
      }
    }
}

// ------------------------------------------------------------ attention -----
// 32x32x16 MFMA flash attention, S^T orientation. 4 waves x 32 q, 64-key
// tiles. EXACT R3 body — measured best 95.7us (reproduced 95.4-95.6 in R14);
// all variants regressed: dbuf=103.6 (spill), 2-wave=100.7, pkcvt=100.0.
// Issue-bound local optimum — FROZEN. XCD grid swizzle (FETCH 139->24.6MB).
__global__ __launch_bounds__(256)
__attribute__((amdgpu_waves_per_eu(4, 4)))
void k_attn(const u16* __restrict__ Qb, const u16* __restrict__ Kb,
            const u16* __restrict__ Vt, const float* __restrict__ relb,
            u16* __restrict__ Obf) {
  __shared__ u16 Ks[64 * 64];      // [key][xor-swizzled 8-elem d blocks] 8 KB
  __shared__ u16 VTs[64 * 64];     // [d][xor-swizzled 8-key blocks]      8 KB
  __shared__ float biasL[32];

  const int tid = threadIdx.x;
  const int wave = tid >> 6, lane = tid & 63;
  const int l32 = lane & 31, hi = lane >> 5;
  // XCD swizzle: lin%8 = XCD (round-robin dispatch). Each XCD gets 8 whole
  // bh (4MB K/V = its L2); consecutive blocks within an XCD share bh.
  const int lin = blockIdx.x;          // 0..1023
  const int xcd = lin & 7;
  const int ixc = lin >> 3;            // 0..127
  const int bh = xcd * 8 + (ixc & 7);  // 0..63
  const int qt = ixc >> 3;             // 0..15
  const int h = bh & (NHEAD - 1);
  const size_t base = (size_t)bh * SEQT * HDIM;
  const int qa = qt * 128 + wave * 32;

  if (tid < 31) biasL[tid] = relb[tid * NHEAD + h] * LOG2E;
  const float bLo = relb[0 * NHEAD + h] * LOG2E;
  const float bHi = relb[30 * NHEAD + h] * LOG2E;
  const float CL = 0.125f * LOG2E;

  // Q as B-operand frags: slot (hi,e) -> d = ds*16 + hi*8 + e, n = qa+l32
  bf16x8 bq[4];
  {
    const u16* qp = Qb + base + (size_t)(qa + l32) * HDIM + hi * 8;
    for (int ds = 0; ds < 4; ++ds) bq[ds] = *(const bf16x8*)(qp + ds * 16);
  }

  f32x16 Oacc[2] = {};
  f32x2 ls2 = {};

  // staging addresses (loop-invariant bases)
  const int rl = lane >> 3, gb = lane & 7;
  const int row0 = wave * 8 + rl, row1 = row0 + 32;
  const u16* kgp0 = Kb + base + (size_t)row0 * HDIM + ((gb ^ (row0 & 7)) << 3);
  const u16* kgp1 = Kb + base + (size_t)row1 * HDIM + ((gb ^ (row1 & 7)) << 3);
  const u16* vgp0 = Vt + base + (size_t)row0 * SEQT + ((gb ^ (row0 & 7)) << 3);
  const u16* vgp1 = Vt + base + (size_t)row1 * SEQT + ((gb ^ (row1 & 7)) << 3);
  u16* ksl0 = &Ks[wave * 512 + lane * 8];
  u16* ksl1 = ksl0 + 2048;
  u16* vsl0 = &VTs[wave * 512 + lane * 8];
  u16* vsl1 = vsl0 + 2048;

  // loop-invariant LDS read offsets (u16 indices), 8 + 8
  int akoff[8], avoff[8];
#pragma unroll
  for (int kgrp = 0; kgrp < 2; ++kgrp) {
    const int key = kgrp * 32 + l32;
#pragma unroll
    for (int ds = 0; ds < 4; ++ds)
      akoff[kgrp * 4 + ds] = key * 64 + (((ds * 2 + hi) ^ (key & 7)) << 3);
#pragma unroll
    for (int ks = 0; ks < 2; ++ks)
#pragma unroll
      for (int dg = 0; dg < 2; ++dg) {
        const int d = dg * 32 + l32;
        const int blk = kgrp * 4 + ks * 2 + hi;
        avoff[(kgrp * 2 + ks) * 2 + dg] = d * 64 + ((blk ^ (d & 7)) << 3);
      }
  }

  for (int kt2 = 0; kt2 < 32; ++kt2) {
    const int k0 = kt2 * 64;
    __syncthreads();
    LDS_GLD16(kgp0 + (size_t)k0 * HDIM, ksl0);
    LDS_GLD16(kgp1 + (size_t)k0 * HDIM, ksl1);
    LDS_GLD16(vgp0 + k0, vsl0);
    LDS_GLD16(vgp1 + k0, vsl1);
    __syncthreads();

#pragma unroll
    for (int kgrp = 0; kgrp < 2; ++kgrp) {
      const int kb = k0 + kgrp * 32;
      // ---- S^T = K Q^T over 32 keys x 32 q ----
      f32x16 c = {};
#pragma unroll
      for (int ds = 0; ds < 4; ++ds) {
        bf16x8 ak = *(const bf16x8*)&Ks[akoff[kgrp * 4 + ds]];
        c = __builtin_amdgcn_mfma_f32_32x32x16_bf16(ak, bq[ds], c, 0, 0, 0);
      }

      // ---- softmax (no max): p = exp2(s*CL + bias) in place ----
      const int dmin = kb - (qa + 31);
      if (dmin >= 15 || kb + 31 - qa <= -15) {  // wave-uniform far tile
        const float ub = (dmin >= 15) ? bHi : bLo;
#pragma unroll
        for (int i = 0; i < 16; ++i)
          c[i] = __builtin_amdgcn_exp2f(fmaf(c[i], CL, ub));
      } else {
        const int dbase = kb + 4 * hi - (qa + l32);
#pragma unroll
        for (int i = 0; i < 16; ++i) {
          int d = dbase + (i & 3) + 8 * (i >> 2);
          d = d < -15 ? -15 : (d > 15 ? 15 : d);
          c[i] = __builtin_amdgcn_exp2f(fmaf(c[i], CL, biasL[d + 15]));
        }
      }
      // l-sum (packed pairwise)
      {
        f32x2 s0 = {c[0], c[1]}, s1 = {c[2], c[3]};
        f32x2 s2 = {c[4], c[5]}, s3 = {c[6], c[7]};
        f32x2 s4 = {c[8], c[9]}, s5 = {c[10], c[11]};
        f32x2 s6 = {c[12], c[13]}, s7 = {c[14], c[15]};
        ls2 += ((s0 + s1) + (s2 + s3)) + ((s4 + s5) + (s6 + s7));
      }

      // ---- pack P into PV B-operands (in-lane, no LDS) ----
      uint32_t p[8];
#pragma unroll
      for (int i = 0; i < 8; ++i) p[i] = pkbf(c[2 * i], c[2 * i + 1]);

      // ---- PV: O[d][q] += V[d][key] P[key][q], k-chunks of 16 ----
#pragma unroll
      for (int ks = 0; ks < 2; ++ks) {
        bf16x8 bp = mk_bf8(p[ks * 4 + 0], p[ks * 4 + 1], p[ks * 4 + 2],
                           p[ks * 4 + 3]);
#pragma unroll
        for (int dg = 0; dg < 2; ++dg) {
          bf16x8 av = *(const bf16x8*)&VTs[avoff[(kgrp * 2 + ks) * 2 + dg]];
          Oacc[dg] = __builtin_amdgcn_mfma_f32_32x32x16_bf16(av, bp, Oacc[dg],
                                                             0, 0, 0);
        }
      }
    }
  }

  // l-sum: lanes l and l+32 share q, cover disjoint key rows
  float ls = ls2.x + ls2.y;
  ls += __shfl_xor(ls, 32, 64);
  const float rinv = 1.0f / ls;

  // epilogue: lane = fixed t = qa+l32; rows d = dg*32 + 8a + 4hi + {0..3}
  const int b = bh >> 4;
  const int t = qa + l32;
  u16* op = Obf + ((size_t)(b * SEQT + t)) * DMODEL + h * HDIM;
#pragma unroll
  for (int dg = 0; dg < 2; ++dg)
#pragma unroll
    for (int a = 0; a < 4; ++a) {
      uint2 w;
      w.x = pkbf(Oacc[dg][4 * a + 0] * rinv, Oacc[dg][4 * a + 1] * rinv);
      w.y = pkbf(Oacc[dg][4 * a + 2] * rinv, Oacc[dg][4 * a + 3] * rinv);
      *(uint2*)(op + dg * 32 + 8 * a + 4 * hi) = w;
    }
}

// --------------------------------------------------------------- launch -----
extern "C" void kernel_launch(void* const* d_in, const int* in_sizes, int n_in,
                              void* d_out, int out_size, void* d_ws,
                              size_t ws_size, hipStream_t stream) {
  const float* x = (const float*)d_in[0];
  const float* Wq = (const float*)d_in[1];
  const float* bq = (const float*)d_in[2];
  const float* Wk = (const float*)d_in[3];
  const float* bk = (const float*)d_in[4];
  const float* Wv = (const float*)d_in[5];
  const float* bv = (const float*)d_in[6];
  const float* relb = (const float*)d_in[7];
  const float* Wo = (const float*)d_in[8];
  const float* bo = (const float*)d_in[9];
  float* out = (float*)d_out;

  char* ws = (char*)d_ws;
  const size_t SZ_X = (size_t)BATCH * SEQT * DMODEL * 2;  // 16 MB bf16
  const size_t SZ_W = (size_t)DMODEL * DMODEL * 2;        // 2 MB bf16
  u16* xbf = (u16*)(ws);
  u16* Wqb = (u16*)(ws + SZ_X);          // Wq,Wk,Wv contiguous
  u16* Wvb = (u16*)(ws + SZ_X + 2 * SZ_W);
  u16* Wob = (u16*)(ws + SZ_X + 3 * SZ_W);
  u16* Qb = (u16*)(ws + SZ_X + 4 * SZ_W);
  u16* Kb = (u16*)(ws + 2 * SZ_X + 4 * SZ_W);
  u16* Vt = (u16*)(ws + 3 * SZ_X + 4 * SZ_W);
  u16* Obf = (u16*)(ws + 4 * SZ_X + 4 * SZ_W);

  k_convert_all<<<12288, 256, 0, stream>>>(x, Wq, Wk, Wv, Wo, xbf, Wqb, Wob);
  k_gemm_qkvt<<<1536, 256, 0, stream>>>(xbf, Wqb, Wvb, bq, bk, bv, Qb, Kb, Vt);
  k_attn<<<1024, 256, 0, stream>>>(Qb, Kb, Vt, relb, Obf);
  k_gemm_proj<<<512, 256, 0, stream>>>(Obf, Wob, bo, out);
}

// Round 16
// 294.182 us; speedup vs baseline: 1.1405x; 1.1405x over previous
//
#include <hip/hip_runtime.h>
#include <stdint.h>
#include <math.h>

typedef unsigned short u16;
typedef __bf16 bf16x8 __attribute__((ext_vector_type(8)));
typedef float f32x4 __attribute__((ext_vector_type(4)));
typedef float f32x2 __attribute__((ext_vector_type(2)));
typedef float f32x16 __attribute__((ext_vector_type(16)));
typedef unsigned short u16x8 __attribute__((ext_vector_type(8)));
typedef unsigned short u16x4 __attribute__((ext_vector_type(4)));

#define BATCH 4
#define SEQT 2048
#define DMODEL 1024
#define NHEAD 16
#define HDIM 64
#define LOG2E 1.44269504f

#define LDS_GLD16(gp, lp)                                                     \
  __builtin_amdgcn_global_load_lds(                                           \
      (const __attribute__((address_space(1))) void*)(gp),                    \
      (__attribute__((address_space(3))) void*)(lp), 16, 0, 0)

static __device__ __forceinline__ u16 f2bf(float f) {  // RNE
  union { float f; uint32_t u; } c; c.f = f;
  uint32_t u = c.u;
  return (u16)((u + 0x7fffu + ((u >> 16) & 1u)) >> 16);
}
static __device__ __forceinline__ u16 f2bf_fast(float f) {  // round-half-up
  union { float f; uint32_t u; } c; c.f = f;
  return (u16)((c.u + 0x8000u) >> 16);
}
// pack bf16(a) low 16, bf16(b) high 16 (round-half-up)
static __device__ __forceinline__ uint32_t pkbf(float a, float b) {
  union { float f; uint32_t u; } ca, cb; ca.f = a; cb.f = b;
  return __builtin_amdgcn_perm(cb.u + 0x8000u, ca.u + 0x8000u, 0x07060302u);
}
static __device__ __forceinline__ bf16x8 mk_bf8(uint32_t x0, uint32_t x1,
                                                uint32_t x2, uint32_t x3) {
  union { uint32_t u[4]; bf16x8 v; } t;
  t.u[0] = x0; t.u[1] = x1; t.u[2] = x2; t.u[3] = x3;
  return t.v;
}

// ------------------------------------------------------------ convert all ---
__global__ __launch_bounds__(256) void k_convert_all(
    const float* __restrict__ x, const float* __restrict__ Wq,
    const float* __restrict__ Wk, const float* __restrict__ Wv,
    const float* __restrict__ Wo, u16* __restrict__ xbf,
    u16* __restrict__ Wqkv, u16* __restrict__ Wob) {
  const int NX4 = 2097152, NW4 = 262144;
  int i = blockIdx.x * 256 + threadIdx.x;
  const float* s; u16* d; int js, jd;
  if (i < NX4) {
    s = x; d = xbf; js = jd = i;
  } else if (i < NX4 + 3 * NW4) {
    int j = i - NX4;
    int w = j >> 18;
    s = (w == 0) ? Wq : (w == 1) ? Wk : Wv;
    js = j & (NW4 - 1);
    d = Wqkv; jd = j;
  } else {
    s = Wo; d = Wob; js = jd = i - NX4 - 3 * NW4;
  }
  float4 v = ((const float4*)s)[js];
  u16x4 o = {f2bf(v.x), f2bf(v.y), f2bf(v.z), f2bf(v.w)};
  ((u16x4*)d)[jd] = o;
}

// ---------------------------------------------------- QK + VT merged GEMM ---
// blocks [0,1024): C = x * [Wq;Wk]^T (M=8192,N=2048), scatter Q/K [bh][t][hd]
// blocks [1024,1536): V^T = Wv * x^T (M=1024,N=8192), scatter Vt [bh][d][t']
//   with t' key-permuted within 16-groups so attention PV A-frags are
//   single contiguous b128 reads: pos(k)=(k&~15)|((k&4)<<1)|((k&8)>>1)|(k&3).
// R11: XCD-aware L2-locality remap (T1) — verified: total 297.6->295.3.
// R16: REVERT R15's 32x32x16 MFMA (regressed 90->122us: lanes 0-31 reading
//   32 different rows at one 16B column = 32-way bank conflict, 4.4e7
//   SQ_LDS_BANK_CONFLICT). The 16x16x32 quad*8 layout spreads reads over
//   4 column slots — low-conflict. Keep 16x16x32.
__global__ __launch_bounds__(256) void k_gemm_qkvt(
    const u16* __restrict__ xbf, const u16* __restrict__ Wqk,
    const u16* __restrict__ Wv, const float* __restrict__ bq_,
    const float* __restrict__ bk_, const float* __restrict__ bv_,
    u16* __restrict__ dq, u16* __restrict__ dk, u16* __restrict__ Vt) {
  __shared__ u16 As[128 * 64];
  __shared__ u16 Bs[128 * 64];

  const int bid = blockIdx.x;
  const bool isQK = bid < 1024;
  const u16 *Ap, *Bp;
  int m0, n0;
  if (isQK) {
    const int c = bid & 7;        // XCD (dispatch round-robin)
    const int j = bid >> 3;       // 0..127
    m0 = (c * 8 + (j & 7)) * 128; // 64 m-panels; 8 per XCD, L2-resident
    n0 = (j >> 3) * 128;          // 0..15, varies slowest
    Ap = xbf; Bp = Wqk;
  } else {
    const int i2 = bid - 1024;    // 0..511 (XCD of bid = i2%8 since 1024%8=0)
    const int c = i2 & 7;
    const int j = i2 >> 3;        // 0..63
    m0 = (j >> 3) * 128;          // 0..7 (Wv panels, hot 8-consecutive)
    n0 = (c * 8 + (j & 7)) * 128; // 64 n-panels; 8 per XCD, L2-resident
    Ap = Wv; Bp = xbf;
  }

  const int tid = threadIdx.x;
  const int wave = tid >> 6, lane = tid & 63;
  const int quad = lane >> 4, l16 = lane & 15;
  const int wm = wave & 1, wn = wave >> 1;
  const int lrow = lane >> 3, lcol = (lane & 7) * 8;

  f32x4 acc[4][4] = {};

  for (int kt = 0; kt < 1024; kt += 64) {
    __syncthreads();
    for (int c = 0; c < 4; ++c) {
      int rr = (wave * 4 + c) * 8 + lrow;
      LDS_GLD16(Ap + (size_t)(m0 + rr) * 1024 + kt + lcol,
                &As[(wave * 4 + c) * 512]);
      LDS_GLD16(Bp + (size_t)(n0 + rr) * 1024 + kt + lcol,
                &Bs[(wave * 4 + c) * 512]);
    }
    __syncthreads();
    for (int kh = 0; kh < 2; ++kh) {
      bf16x8 af[4], bfr[4];
      for (int mt = 0; mt < 4; ++mt)
        af[mt] = *(const bf16x8*)&As[(wm * 64 + mt * 16 + l16) * 64 + kh * 32 +
                                     quad * 8];
      for (int nt = 0; nt < 4; ++nt)
        bfr[nt] = *(const bf16x8*)&Bs[(wn * 64 + nt * 16 + l16) * 64 + kh * 32 +
                                      quad * 8];
      for (int mt = 0; mt < 4; ++mt)
        for (int nt = 0; nt < 4; ++nt)
          acc[mt][nt] = __builtin_amdgcn_mfma_f32_16x16x32_bf16(
              af[mt], bfr[nt], acc[mt][nt], 0, 0, 0);
    }
  }

  if (isQK) {
    u16* dst = (n0 < 1024) ? dq : dk;
    const float* bias = (n0 < 1024) ? bq_ : bk_;
    for (int mt = 0; mt < 4; ++mt)
      for (int nt = 0; nt < 4; ++nt) {
        int nn = (n0 + wn * 64 + nt * 16 + l16) & 1023;
        float bv = bias[nn];
        int h = nn >> 6, hd = nn & 63;
        for (int r = 0; r < 4; ++r) {
          int m = m0 + wm * 64 + mt * 16 + quad * 4 + r;
          int b = m >> 11, t = m & 2047;
          dst[(((size_t)b * NHEAD + h) * SEQT + t) * HDIM + hd] =
              f2bf_fast(acc[mt][nt][r] + bv);
        }
      }
  } else {
    for (int mt = 0; mt < 4; ++mt)
      for (int nt = 0; nt < 4; ++nt) {
        int n = n0 + wn * 64 + nt * 16 + l16;
        int b = n >> 11, t = n & 2047;
        int tp = (t & ~15) | ((t & 4) << 1) | ((t & 8) >> 1) | (t & 3);
        for (int r = 0; r < 4; ++r) {
          int m = m0 + wm * 64 + mt * 16 + quad * 4 + r;
          float v = acc[mt][nt][r] + bv_[m];
          Vt[((size_t)(b * NHEAD + (m >> 6)) * HDIM + (m & 63)) * SEQT + tp] =
              f2bf_fast(v);
        }
      }
  }
}

// ------------------------------------------------------------ out-proj ------
// R11: 1-D grid 512, XCD remap: XCD c owns m-panels [c*8, c*8+8) (2MB of
// Obf, L2-resident), n0 slowest so each Wo panel is hot 8-consecutive.
// R16: reverted to 16x16x32 (see qkvt comment).
__global__ __launch_bounds__(256) void k_gemm_proj(const u16* __restrict__ A,
                                                   const u16* __restrict__ Bm,
                                                   const float* __restrict__ bias,
                                                   float* __restrict__ out) {
  __shared__ u16 As[128 * 64];
  __shared__ u16 Bs[128 * 64];

  const int tid = threadIdx.x;
  const int wave = tid >> 6, lane = tid & 63;
  const int quad = lane >> 4, l16 = lane & 15;
  const int wm = wave & 1, wn = wave >> 1;
  const int bid = blockIdx.x;            // 0..511
  const int xc = bid & 7, j = bid >> 3;  // j 0..63
  const int m0 = (xc * 8 + (j & 7)) * 128;  // 64 m-panels; 8 per XCD
  const int n0 = (j >> 3) * 128;            // 0..7
  const int lrow = lane >> 3, lcol = (lane & 7) * 8;

  f32x4 acc[4][4] = {};

  for (int kt = 0; kt < 1024; kt += 64) {
    __syncthreads();
    for (int c = 0; c < 4; ++c) {
      int rr = (wave * 4 + c) * 8 + lrow;
      LDS_GLD16(A + (size_t)(m0 + rr) * 1024 + kt + lcol,
                &As[(wave * 4 + c) * 512]);
      LDS_GLD16(Bm + (size_t)(n0 + rr) * 1024 + kt + lcol,
                &Bs[(wave * 4 + c) * 512]);
    }
    __syncthreads();
    for (int kh = 0; kh < 2; ++kh) {
      bf16x8 af[4], bfr[4];
      for (int mt = 0; mt < 4; ++mt)
        af[mt] = *(const bf16x8*)&As[(wm * 64 + mt * 16 + l16) * 64 + kh * 32 +
                                     quad * 8];
      for (int nt = 0; nt < 4; ++nt)
        bfr[nt] = *(const bf16x8*)&Bs[(wn * 64 + nt * 16 + l16) * 64 + kh * 32 +
                                      quad * 8];
      for (int mt = 0; mt < 4; ++mt)
        for (int nt = 0; nt < 4; ++nt)
          acc[mt][nt] = __builtin_amdgcn_mfma_f32_16x16x32_bf16(
              af[mt], bfr[nt], acc[mt][nt], 0, 0, 0);
    }
  }

  for (int mt = 0; mt < 4; ++mt)
    for (int nt = 0; nt < 4; ++nt) {
      int n = n0 + wn * 64 + nt * 16 + l16;
      float bv = bias[n];
      for (int r = 0; r < 4; ++r) {
        int m = m0 + wm * 64 + mt * 16 + quad * 4 + r;
        out[(size_t)m * 1024 + n] = acc[mt][nt][r] + bv;
      }
    }
}

// ------------------------------------------------------------ attention -----
// 32x32x16 MFMA flash attention, S^T orientation. 4 waves x 32 q, 64-key
// tiles. EXACT R3 body — measured best 95.7us (reproduced 95.4-95.6 in R14);
// all variants regressed: dbuf=103.6 (spill), 2-wave=100.7, pkcvt=100.0.
// Issue-bound local optimum — FROZEN. XCD grid swizzle (FETCH 139->24.6MB).
__global__ __launch_bounds__(256)
__attribute__((amdgpu_waves_per_eu(4, 4)))
void k_attn(const u16* __restrict__ Qb, const u16* __restrict__ Kb,
            const u16* __restrict__ Vt, const float* __restrict__ relb,
            u16* __restrict__ Obf) {
  __shared__ u16 Ks[64 * 64];      // [key][xor-swizzled 8-elem d blocks] 8 KB
  __shared__ u16 VTs[64 * 64];     // [d][xor-swizzled 8-key blocks]      8 KB
  __shared__ float biasL[32];

  const int tid = threadIdx.x;
  const int wave = tid >> 6, lane = tid & 63;
  const int l32 = lane & 31, hi = lane >> 5;
  // XCD swizzle: lin%8 = XCD (round-robin dispatch). Each XCD gets 8 whole
  // bh (4MB K/V = its L2); consecutive blocks within an XCD share bh.
  const int lin = blockIdx.x;          // 0..1023
  const int xcd = lin & 7;
  const int ixc = lin >> 3;            // 0..127
  const int bh = xcd * 8 + (ixc & 7);  // 0..63
  const int qt = ixc >> 3;             // 0..15
  const int h = bh & (NHEAD - 1);
  const size_t base = (size_t)bh * SEQT * HDIM;
  const int qa = qt * 128 + wave * 32;

  if (tid < 31) biasL[tid] = relb[tid * NHEAD + h] * LOG2E;
  const float bLo = relb[0 * NHEAD + h] * LOG2E;
  const float bHi = relb[30 * NHEAD + h] * LOG2E;
  const float CL = 0.125f * LOG2E;

  // Q as B-operand frags: slot (hi,e) -> d = ds*16 + hi*8 + e, n = qa+l32
  bf16x8 bq[4];
  {
    const u16* qp = Qb + base + (size_t)(qa + l32) * HDIM + hi * 8;
    for (int ds = 0; ds < 4; ++ds) bq[ds] = *(const bf16x8*)(qp + ds * 16);
  }

  f32x16 Oacc[2] = {};
  f32x2 ls2 = {};

  // staging addresses (loop-invariant bases)
  const int rl = lane >> 3, gb = lane & 7;
  const int row0 = wave * 8 + rl, row1 = row0 + 32;
  const u16* kgp0 = Kb + base + (size_t)row0 * HDIM + ((gb ^ (row0 & 7)) << 3);
  const u16* kgp1 = Kb + base + (size_t)row1 * HDIM + ((gb ^ (row1 & 7)) << 3);
  const u16* vgp0 = Vt + base + (size_t)row0 * SEQT + ((gb ^ (row0 & 7)) << 3);
  const u16* vgp1 = Vt + base + (size_t)row1 * SEQT + ((gb ^ (row1 & 7)) << 3);
  u16* ksl0 = &Ks[wave * 512 + lane * 8];
  u16* ksl1 = ksl0 + 2048;
  u16* vsl0 = &VTs[wave * 512 + lane * 8];
  u16* vsl1 = vsl0 + 2048;

  // loop-invariant LDS read offsets (u16 indices), 8 + 8
  int akoff[8], avoff[8];
#pragma unroll
  for (int kgrp = 0; kgrp < 2; ++kgrp) {
    const int key = kgrp * 32 + l32;
#pragma unroll
    for (int ds = 0; ds < 4; ++ds)
      akoff[kgrp * 4 + ds] = key * 64 + (((ds * 2 + hi) ^ (key & 7)) << 3);
#pragma unroll
    for (int ks = 0; ks < 2; ++ks)
#pragma unroll
      for (int dg = 0; dg < 2; ++dg) {
        const int d = dg * 32 + l32;
        const int blk = kgrp * 4 + ks * 2 + hi;
        avoff[(kgrp * 2 + ks) * 2 + dg] = d * 64 + ((blk ^ (d & 7)) << 3);
      }
  }

  for (int kt2 = 0; kt2 < 32; ++kt2) {
    const int k0 = kt2 * 64;
    __syncthreads();
    LDS_GLD16(kgp0 + (size_t)k0 * HDIM, ksl0);
    LDS_GLD16(kgp1 + (size_t)k0 * HDIM, ksl1);
    LDS_GLD16(vgp0 + k0, vsl0);
    LDS_GLD16(vgp1 + k0, vsl1);
    __syncthreads();

#pragma unroll
    for (int kgrp = 0; kgrp < 2; ++kgrp) {
      const int kb = k0 + kgrp * 32;
      // ---- S^T = K Q^T over 32 keys x 32 q ----
      f32x16 c = {};
#pragma unroll
      for (int ds = 0; ds < 4; ++ds) {
        bf16x8 ak = *(const bf16x8*)&Ks[akoff[kgrp * 4 + ds]];
        c = __builtin_amdgcn_mfma_f32_32x32x16_bf16(ak, bq[ds], c, 0, 0, 0);
      }

      // ---- softmax (no max): p = exp2(s*CL + bias) in place ----
      const int dmin = kb - (qa + 31);
      if (dmin >= 15 || kb + 31 - qa <= -15) {  // wave-uniform far tile
        const float ub = (dmin >= 15) ? bHi : bLo;
#pragma unroll
        for (int i = 0; i < 16; ++i)
          c[i] = __builtin_amdgcn_exp2f(fmaf(c[i], CL, ub));
      } else {
        const int dbase = kb + 4 * hi - (qa + l32);
#pragma unroll
        for (int i = 0; i < 16; ++i) {
          int d = dbase + (i & 3) + 8 * (i >> 2);
          d = d < -15 ? -15 : (d > 15 ? 15 : d);
          c[i] = __builtin_amdgcn_exp2f(fmaf(c[i], CL, biasL[d + 15]));
        }
      }
      // l-sum (packed pairwise)
      {
        f32x2 s0 = {c[0], c[1]}, s1 = {c[2], c[3]};
        f32x2 s2 = {c[4], c[5]}, s3 = {c[6], c[7]};
        f32x2 s4 = {c[8], c[9]}, s5 = {c[10], c[11]};
        f32x2 s6 = {c[12], c[13]}, s7 = {c[14], c[15]};
        ls2 += ((s0 + s1) + (s2 + s3)) + ((s4 + s5) + (s6 + s7));
      }

      // ---- pack P into PV B-operands (in-lane, no LDS) ----
      uint32_t p[8];
#pragma unroll
      for (int i = 0; i < 8; ++i) p[i] = pkbf(c[2 * i], c[2 * i + 1]);

      // ---- PV: O[d][q] += V[d][key] P[key][q], k-chunks of 16 ----
#pragma unroll
      for (int ks = 0; ks < 2; ++ks) {
        bf16x8 bp = mk_bf8(p[ks * 4 + 0], p[ks * 4 + 1], p[ks * 4 + 2],
                           p[ks * 4 + 3]);
#pragma unroll
        for (int dg = 0; dg < 2; ++dg) {
          bf16x8 av = *(const bf16x8*)&VTs[avoff[(kgrp * 2 + ks) * 2 + dg]];
          Oacc[dg] = __builtin_amdgcn_mfma_f32_32x32x16_bf16(av, bp, Oacc[dg],
                                                             0, 0, 0);
        }
      }
    }
  }

  // l-sum: lanes l and l+32 share q, cover disjoint key rows
  float ls = ls2.x + ls2.y;
  ls += __shfl_xor(ls, 32, 64);
  const float rinv = 1.0f / ls;

  // epilogue: lane = fixed t = qa+l32; rows d = dg*32 + 8a + 4hi + {0..3}
  const int b = bh >> 4;
  const int t = qa + l32;
  u16* op = Obf + ((size_t)(b * SEQT + t)) * DMODEL + h * HDIM;
#pragma unroll
  for (int dg = 0; dg < 2; ++dg)
#pragma unroll
    for (int a = 0; a < 4; ++a) {
      uint2 w;
      w.x = pkbf(Oacc[dg][4 * a + 0] * rinv, Oacc[dg][4 * a + 1] * rinv);
      w.y = pkbf(Oacc[dg][4 * a + 2] * rinv, Oacc[dg][4 * a + 3] * rinv);
      *(uint2*)(op + dg * 32 + 8 * a + 4 * hi) = w;
    }
}

// --------------------------------------------------------------- launch -----
extern "C" void kernel_launch(void* const* d_in, const int* in_sizes, int n_in,
                              void* d_out, int out_size, void* d_ws,
                              size_t ws_size, hipStream_t stream) {
  const float* x = (const float*)d_in[0];
  const float* Wq = (const float*)d_in[1];
  const float* bq = (const float*)d_in[2];
  const float* Wk = (const float*)d_in[3];
  const float* bk = (const float*)d_in[4];
  const float* Wv = (const float*)d_in[5];
  const float* bv = (const float*)d_in[6];
  const float* relb = (const float*)d_in[7];
  const float* Wo = (const float*)d_in[8];
  const float* bo = (const float*)d_in[9];
  float* out = (float*)d_out;

  char* ws = (char*)d_ws;
  const size_t SZ_X = (size_t)BATCH * SEQT * DMODEL * 2;  // 16 MB bf16
  const size_t SZ_W = (size_t)DMODEL * DMODEL * 2;        // 2 MB bf16
  u16* xbf = (u16*)(ws);
  u16* Wqb = (u16*)(ws + SZ_X);          // Wq,Wk,Wv contiguous
  u16* Wvb = (u16*)(ws + SZ_X + 2 * SZ_W);
  u16* Wob = (u16*)(ws + SZ_X + 3 * SZ_W);
  u16* Qb = (u16*)(ws + SZ_X + 4 * SZ_W);
  u16* Kb = (u16*)(ws + 2 * SZ_X + 4 * SZ_W);
  u16* Vt = (u16*)(ws + 3 * SZ_X + 4 * SZ_W);
  u16* Obf = (u16*)(ws + 4 * SZ_X + 4 * SZ_W);

  k_convert_all<<<12288, 256, 0, stream>>>(x, Wq, Wk, Wv, Wo, xbf, Wqb, Wob);
  k_gemm_qkvt<<<1536, 256, 0, stream>>>(xbf, Wqb, Wvb, bq, bk, bv, Qb, Kb, Vt);
  k_attn<<<1024, 256, 0, stream>>>(Qb, Kb, Vt, relb, Obf);
  k_gemm_proj<<<512, 256, 0, stream>>>(Obf, Wob, bo, out);
}